// Round 7
// baseline (414.083 us; speedup 1.0000x reference)
//
#include <hip/hip_runtime.h>
#include <math.h>

// DigitCaps dynamic routing. B=256, R=1152, C=10, O=16, I=8, 3 iters.
// SINGLE persistent dispatch (256 blocks x 256 thr), hand-rolled flag barrier:
//   arrival = per-block store to own 64B-padded flag (parallel, no RMW chain);
//   block 0's threads poll the 256 flags, then publish a release word.
//   Epochs monotonic 1..7; 0xAA ws-poison = negative int -> no init needed.
// Phases per iter (R6 kernels verbatim, as device funcs on one LDS union):
//   gemm (fused softmax, split-K 128x2 -> part) | reduce+squash -> v/out |
//   gtdot (G=X^T.V tile -> LDS -> W-dot -> atomicAdd bij)
// grid.sync() measured ~45us/sync (R5) — flat single-counter barrier; this
// replaces it. 8 dispatches x ~10us boundary -> 1 dispatch + 7 x ~2us.

#define B_ 256
#define R_ 1152
#define N_ 160      // C*O
#define K_ 9216     // R*I
#define NS 128      // K splits of 72 (9 routes)
#define KB 72
#define KC 24       // K per LDS stage (3 routes)

// workspace layout (float offsets)
#define PART_SZ (2*NS*128*N_)   // 5,242,880 floats (21 MB)
#define BIJ_SZ  (R_*10)
#define V_SZ    (B_*N_)
#define FLAG_OFF (PART_SZ+BIJ_SZ+V_SZ)   // int flags live here (64B strided)

#define SMF 11880   // LDS union: 72*165 floats = 47.5 KB

// ---------------------------------------------------------------------------
// flag barrier: block 0 collects, then releases. e = 1..7 monotonic.
__device__ __forceinline__ void gbar(int* flags, int* rel, int e) {
    __syncthreads();
    if (blockIdx.x == 0) {
        const int t = threadIdx.x;
        if (t > 0) {   // poll block t's arrival flag
            int* f = flags + t * 16;
            while (__hip_atomic_load(f, __ATOMIC_ACQUIRE,
                                     __HIP_MEMORY_SCOPE_AGENT) < e)
                __builtin_amdgcn_s_sleep(1);
        }
        __syncthreads();
        if (t == 0)
            __hip_atomic_store(rel, e, __ATOMIC_RELEASE,
                               __HIP_MEMORY_SCOPE_AGENT);
    } else {
        if (threadIdx.x == 0) {
            __hip_atomic_store(flags + blockIdx.x * 16, e, __ATOMIC_RELEASE,
                               __HIP_MEMORY_SCOPE_AGENT);
            while (__hip_atomic_load(rel, __ATOMIC_ACQUIRE,
                                     __HIP_MEMORY_SCOPE_AGENT) < e)
                __builtin_amdgcn_s_sleep(1);
        }
        __syncthreads();
    }
}

// ---------------------------------------------------------------------------
// part[bt,ks][128x160] = X[128 b][72 k] * (softmax_r(bij) ⊙ W)[72 k][160 n]
__device__ __forceinline__ void gemm_phase(const float* __restrict__ X,
                                           const float* __restrict__ W,
                                           float* bij, float* part,
                                           float* SM, int it) {
    float* As  = SM;           // [24][128] transposed
    float* Bs  = SM + 3072;    // [24][16 groups of 12]
    float* cs  = SM + 7680;    // 90
    float* red = SM + 7776;    // 40
    float* dsm = SM + 7816;    // 10
    const int tid = threadIdx.x;
    const int ks = blockIdx.x >> 1, bt = blockIdx.x & 1;
    const int b0 = bt * 128, k0 = ks * KB, r0 = ks * 9;

    if (it == 0) {
        if (tid < 90) cs[tid] = 1.0f / 1152.0f;
        if (bt == 0 && tid < 90) bij[r0 * 10 + tid] = 0.0f;  // init for gtdot
    } else {
        float dcol[10];
        #pragma unroll
        for (int c = 0; c < 10; ++c) dcol[c] = 0.0f;
        for (int r = tid; r < R_; r += 256) {
            #pragma unroll
            for (int c = 0; c < 10; ++c) dcol[c] += __expf(bij[r * 10 + c]);
        }
        const int lane = tid & 63, wv = tid >> 6;
        #pragma unroll
        for (int c = 0; c < 10; ++c) {
            float s = dcol[c];
            #pragma unroll
            for (int off = 32; off > 0; off >>= 1) s += __shfl_down(s, off);
            if (lane == 0) red[wv * 10 + c] = s;
        }
        __syncthreads();
        if (tid < 10)
            dsm[tid] = red[tid] + red[10 + tid] + red[20 + tid] + red[30 + tid];
        __syncthreads();
        if (tid < 90) {
            int rr = tid / 10, cc = tid - rr * 10;
            cs[tid] = __expf(bij[(r0 + rr) * 10 + cc]) / dsm[cc];
        }
    }

    float acc[8][10];
    #pragma unroll
    for (int i = 0; i < 8; ++i)
        #pragma unroll
        for (int j = 0; j < 10; ++j) acc[i][j] = 0.0f;

    const int rg = tid >> 4;   // 16 groups x 8 b-rows
    const int cg = tid & 15;   // 16 groups x 10 n-cols

    for (int st = 0; st < 3; ++st) {
        __syncthreads();
        const int kc = k0 + st * KC;
        #pragma unroll
        for (int j = 0; j < 3; ++j) {           // A: 768 float4, transposed
            int q = j * 256 + tid;
            int bb = q / 6, kf = q - bb * 6;
            float4 a = *(const float4*)(X + (size_t)(b0 + bb) * K_ + kc + kf * 4);
            As[(kf * 4 + 0) * 128 + bb] = a.x;
            As[(kf * 4 + 1) * 128 + bb] = a.y;
            As[(kf * 4 + 2) * 128 + bb] = a.z;
            As[(kf * 4 + 3) * 128 + bb] = a.w;
        }
        const float* Wsl = W + (size_t)(r0 + st * 3) * 1280;
        #pragma unroll
        for (int j = 0; j < 4; ++j) {           // B: 960 float4, c-scaled
            int q = j * 256 + tid;
            if (q < 960) {
                int rl = q / 320;
                int rem = q - rl * 320;
                int c = rem >> 5;
                int o = (rem & 31) >> 1;
                int i4 = rem & 1;
                float4 w = *(const float4*)(Wsl + (size_t)q * 4);
                float sc = cs[(st * 3 + rl) * 10 + c];
                int nn = c * 16 + o;
                int grp = nn / 10;
                int pos = grp * 12 + (nn - grp * 10);
                int kk = rl * 8 + i4 * 4;
                Bs[(kk + 0) * 192 + pos] = w.x * sc;
                Bs[(kk + 1) * 192 + pos] = w.y * sc;
                Bs[(kk + 2) * 192 + pos] = w.z * sc;
                Bs[(kk + 3) * 192 + pos] = w.w * sc;
            }
        }
        __syncthreads();
        #pragma unroll 6
        for (int kk = 0; kk < KC; ++kk) {
            float4 a0 = *(const float4*)(&As[kk * 128 + rg * 8]);
            float4 a1 = *(const float4*)(&As[kk * 128 + rg * 8 + 4]);
            float4 v0 = *(const float4*)(&Bs[kk * 192 + cg * 12]);
            float4 v1 = *(const float4*)(&Bs[kk * 192 + cg * 12 + 4]);
            float2 v2 = *(const float2*)(&Bs[kk * 192 + cg * 12 + 8]);
            float av[8] = {a0.x, a0.y, a0.z, a0.w, a1.x, a1.y, a1.z, a1.w};
            float bv[10] = {v0.x, v0.y, v0.z, v0.w, v1.x, v1.y, v1.z, v1.w,
                            v2.x, v2.y};
            #pragma unroll
            for (int i = 0; i < 8; ++i)
                #pragma unroll
                for (int j = 0; j < 10; ++j) acc[i][j] += av[i] * bv[j];
        }
    }
    float* P = part + (size_t)(bt * NS + ks) * (128 * N_);
    #pragma unroll
    for (int i = 0; i < 8; ++i)
        #pragma unroll
        for (int j = 0; j < 10; ++j)
            P[(rg * 8 + i) * N_ + cg * 10 + j] = acc[i][j];
}

// ---------------------------------------------------------------------------
// block blk reduces batch-row b=blk: 160 outputs, 128-way split-K sum + squash
__device__ __forceinline__ void reduce_phase(const float* __restrict__ part,
                                             float* __restrict__ o) {
    const int tid = threadIdx.x, b = blockIdx.x;
    if (tid < 160) {
        int bt = b >> 7, row = b & 127;
        const float* p = part + (size_t)bt * NS * (128 * N_) + row * N_ + tid;
        float s = 0.0f;
        #pragma unroll 8
        for (int ks = 0; ks < NS; ++ks) s += p[(size_t)ks * (128 * N_)];
        o[b * N_ + tid] = s * fabsf(s) / (1.0f + s * s);
    }
}

// ---------------------------------------------------------------------------
// (kt,bh): G_partial[72x160] over b-half -> LDS -> W-dot -> atomicAdd bij
__device__ __forceinline__ void gtdot_phase(const float* __restrict__ X,
                                            const float* __restrict__ W,
                                            const float* __restrict__ V,
                                            float* bij, float* SM) {
    float* Xs = SM;            // [32][96] (8 groups of 12)
    float* Vs = SM + 3072;     // [160][33] transposed
    float* LG = SM;            // [72][165]
    const int tid = threadIdx.x;
    const int kt = blockIdx.x >> 1, bh = blockIdx.x & 1;
    const int k0 = kt * 72, r0 = kt * 9, b0 = bh * 128;
    const int rg = tid >> 5;   // 8 groups x 9 k-rows
    const int cg = tid & 31;   // 32 groups x 5 n-cols
    float acc[9][5];
    #pragma unroll
    for (int i = 0; i < 9; ++i)
        #pragma unroll
        for (int j = 0; j < 5; ++j) acc[i][j] = 0.0f;

    for (int sb = 0; sb < 4; ++sb) {
        __syncthreads();
        const int bb0 = b0 + sb * 32;
        #pragma unroll
        for (int j = 0; j < 3; ++j) {           // X: 576 float4
            int q = j * 256 + tid;
            if (q < 576) {
                int bb = q / 18, kf = q - bb * 18;
                float4 a = *(const float4*)(X + (size_t)(bb0 + bb) * K_ + k0 + kf * 4);
                float c4[4] = {a.x, a.y, a.z, a.w};
                #pragma unroll
                for (int m = 0; m < 4; ++m) {
                    int kk = kf * 4 + m;
                    int gp = kk / 9;
                    Xs[bb * 96 + gp * 12 + (kk - gp * 9)] = c4[m];
                }
            }
        }
        #pragma unroll
        for (int j = 0; j < 5; ++j) {           // V: 1280 float4, transpose
            int q = j * 256 + tid;
            int bb = q / 40, nf = q - bb * 40;
            float4 v = *(const float4*)(V + (size_t)(bb0 + bb) * N_ + nf * 4);
            int n = nf * 4;
            Vs[(n + 0) * 33 + bb] = v.x;
            Vs[(n + 1) * 33 + bb] = v.y;
            Vs[(n + 2) * 33 + bb] = v.z;
            Vs[(n + 3) * 33 + bb] = v.w;
        }
        __syncthreads();
        #pragma unroll 4
        for (int b = 0; b < 32; ++b) {
            float4 x0 = *(const float4*)(&Xs[b * 96 + rg * 12]);
            float4 x1 = *(const float4*)(&Xs[b * 96 + rg * 12 + 4]);
            float x8 = Xs[b * 96 + rg * 12 + 8];
            float xr[9] = {x0.x, x0.y, x0.z, x0.w, x1.x, x1.y, x1.z, x1.w, x8};
            float bv[5];
            #pragma unroll
            for (int j = 0; j < 5; ++j) bv[j] = Vs[(cg * 5 + j) * 33 + b];
            #pragma unroll
            for (int i = 0; i < 9; ++i)
                #pragma unroll
                for (int j = 0; j < 5; ++j) acc[i][j] += xr[i] * bv[j];
        }
    }
    __syncthreads();
    #pragma unroll
    for (int i = 0; i < 9; ++i)
        #pragma unroll
        for (int j = 0; j < 5; ++j)
            LG[(rg * 9 + i) * 165 + cg * 5 + j] = acc[i][j];
    __syncthreads();
    if (tid < 90) {
        int rl = tid / 10, c = tid - rl * 10;
        int r = r0 + rl;
        const float4* wp = (const float4*)(W + (size_t)r * 1280 + c * 128);
        float s = 0.0f;
        #pragma unroll
        for (int o = 0; o < 16; ++o) {
            float4 wa = wp[o * 2], wb = wp[o * 2 + 1];
            const float* g = &LG[(rl * 8) * 165 + c * 16 + o];
            s += wa.x * g[0]       + wa.y * g[165]     + wa.z * g[2 * 165] +
                 wa.w * g[3 * 165] + wb.x * g[4 * 165] + wb.y * g[5 * 165] +
                 wb.z * g[6 * 165] + wb.w * g[7 * 165];
        }
        atomicAdd(&bij[r * 10 + c], s * (1.0f / B_));
    }
}

// ---------------------------------------------------------------------------
__global__ __launch_bounds__(256) void k_caps(const float* __restrict__ X,
                                              const float* __restrict__ W,
                                              float* part, float* bij,
                                              float* vws, float* out,
                                              int* flags, int* rel) {
    __shared__ float SM[SMF];   // 47.5 KB union
    // it0
    gemm_phase(X, W, bij, part, SM, 0);
    gbar(flags, rel, 1);
    reduce_phase(part, vws);
    gbar(flags, rel, 2);
    gtdot_phase(X, W, vws, bij, SM);
    gbar(flags, rel, 3);
    // it1
    gemm_phase(X, W, bij, part, SM, 1);
    gbar(flags, rel, 4);
    reduce_phase(part, vws);
    gbar(flags, rel, 5);
    gtdot_phase(X, W, vws, bij, SM);
    gbar(flags, rel, 6);
    // it2
    gemm_phase(X, W, bij, part, SM, 2);
    gbar(flags, rel, 7);
    reduce_phase(part, out);
}

// ---------------------------------------------------------------------------
extern "C" void kernel_launch(void* const* d_in, const int* in_sizes, int n_in,
                              void* d_out, int out_size, void* d_ws, size_t ws_size,
                              hipStream_t stream) {
    const float* x = (const float*)d_in[0];   // (256, 1152, 8)
    const float* W = (const float*)d_in[1];   // (1152, 10, 16, 8)
    float* ws    = (float*)d_ws;
    float* part  = ws;
    float* bij   = ws + PART_SZ;
    float* vws   = bij + BIJ_SZ;
    int*   flags = (int*)(ws + FLAG_OFF);     // 256 flags, 64B apart
    int*   rel   = flags + 256 * 16;          // release word
    float* outf  = (float*)d_out;
    // 0xAA poison reads as negative int -> flags/rel need no zeroing:
    // all waits are "< e" with e >= 1, and arrivals store monotonic epochs.
    k_caps<<<256, 256, 0, stream>>>(x, W, part, bij, vws, outf, flags, rel);
}

// Round 8
// 204.185 us; speedup vs baseline: 2.0280x; 2.0280x over previous
//
#include <hip/hip_runtime.h>
#include <math.h>

// DigitCaps dynamic routing. B=256, R=1152, C=10, O=16, I=8, 3 iters.
// 8 dispatches (persistent-kernel global barriers measured ~43us/sync in BOTH
// cg::grid_sync (R5) and hand-rolled flag-barrier (R7) forms — abandoned;
// dispatch boundary is ~4-10us, strictly cheaper).
//   it 0..2: k_gemm  (fused softmax; 128 K-splits x 2 b-tiles; 8b x 10n/thread)
//            k_reduce (128-way split-K reduce + squash; 1 b-row per block)
//   it 0..1: k_gtdot (G=X^T.V 72k x 160n tile in regs -> LDS -> W-dot ->
//            atomicAdd bij; 2 b-halves; 9k x 5n/thread)
// R8 deltas vs R6: As row stride 128->129 (A-staging scatter had 6-way bank
// conflicts: stride 128 ≡ 0 mod 32 banks -> bank = bb%32, lanes 0..5 collide;
// matches R7's SQ_LDS_BANK_CONFLICT=4.16M), part stores vectorized to float2,
// reduce grid 160->256.

#define B_ 256
#define R_ 1152
#define N_ 160      // C*O
#define K_ 9216     // R*I
#define NS 128      // K splits of 72 (9 routes)
#define KB 72
#define KC 24       // K per LDS stage (3 routes)
#define ASP 129     // As row stride (pad: kills 6-way staging conflicts)

// workspace layout (float offsets)
#define PART_SZ (2*NS*128*N_)   // 5,242,880 floats (21 MB)
#define BIJ_SZ  (R_*10)
#define V_SZ    (B_*N_)

// ---------------------------------------------------------------------------
// part[bt,ks][128x160] = X[128 b][72 k] * (softmax_r(bij) ⊙ W)[72 k][160 n]
// grid 256 = (ks 0..127) x (bt 0..1); thread tile 8b x 10n
__global__ __launch_bounds__(256) void k_gemm(const float* __restrict__ X,
                                              const float* __restrict__ W,
                                              float* __restrict__ bij,
                                              float* __restrict__ part,
                                              int it) {
    __shared__ float As[KC * ASP];   // [k][b] transposed, stride 129
    __shared__ float Bs[KC * 192];   // [k][16 groups of 12]
    __shared__ float cs[90];         // c_ij for this block's 9 routes
    __shared__ float red[40];
    __shared__ float dsm[10];
    const int tid = threadIdx.x;
    const int ks = blockIdx.x >> 1, bt = blockIdx.x & 1;
    const int b0 = bt * 128, k0 = ks * KB, r0 = ks * 9;

    // ---- fused softmax over routes (axis 0), redundant per block ----
    if (it == 0) {
        if (tid < 90) cs[tid] = 1.0f / 1152.0f;
        if (bt == 0 && tid < 90) bij[r0 * 10 + tid] = 0.0f;  // init for gtdot
    } else {
        float dcol[10];
        #pragma unroll
        for (int c = 0; c < 10; ++c) dcol[c] = 0.0f;
        for (int r = tid; r < R_; r += 256) {
            #pragma unroll
            for (int c = 0; c < 10; ++c) dcol[c] += __expf(bij[r * 10 + c]);
        }
        const int lane = tid & 63, wv = tid >> 6;
        #pragma unroll
        for (int c = 0; c < 10; ++c) {
            float s = dcol[c];
            #pragma unroll
            for (int off = 32; off > 0; off >>= 1) s += __shfl_down(s, off);
            if (lane == 0) red[wv * 10 + c] = s;
        }
        __syncthreads();
        if (tid < 10)
            dsm[tid] = red[tid] + red[10 + tid] + red[20 + tid] + red[30 + tid];
        __syncthreads();
        if (tid < 90) {
            int rr = tid / 10, cc = tid - rr * 10;
            cs[tid] = __expf(bij[(r0 + rr) * 10 + cc]) / dsm[cc];
        }
    }

    float acc[8][10];
    #pragma unroll
    for (int i = 0; i < 8; ++i)
        #pragma unroll
        for (int j = 0; j < 10; ++j) acc[i][j] = 0.0f;

    const int rg = tid >> 4;   // 16 groups x 8 b-rows
    const int cg = tid & 15;   // 16 groups x 10 n-cols

    for (int st = 0; st < 3; ++st) {
        __syncthreads();
        const int kc = k0 + st * KC;
        // stage A transposed: 768 float4 (3/thread); ASP=129 de-conflicts
        #pragma unroll
        for (int j = 0; j < 3; ++j) {
            int q = j * 256 + tid;
            int bb = q / 6, kf = q - bb * 6;
            float4 a = *(const float4*)(X + (size_t)(b0 + bb) * K_ + kc + kf * 4);
            As[(kf * 4 + 0) * ASP + bb] = a.x;
            As[(kf * 4 + 1) * ASP + bb] = a.y;
            As[(kf * 4 + 2) * ASP + bb] = a.z;
            As[(kf * 4 + 3) * ASP + bb] = a.w;
        }
        // stage B from native W (3-route slice), c_ij-scaled, 12-padded groups
        const float* Wsl = W + (size_t)(r0 + st * 3) * 1280;
        #pragma unroll
        for (int j = 0; j < 4; ++j) {
            int q = j * 256 + tid;        // float4 idx < 960
            if (q < 960) {
                int rl = q / 320;
                int rem = q - rl * 320;
                int c = rem >> 5;
                int o = (rem & 31) >> 1;
                int i4 = rem & 1;
                float4 w = *(const float4*)(Wsl + (size_t)q * 4);
                float sc = cs[(st * 3 + rl) * 10 + c];
                int nn = c * 16 + o;
                int grp = nn / 10;
                int pos = grp * 12 + (nn - grp * 10);
                int kk = rl * 8 + i4 * 4;
                Bs[(kk + 0) * 192 + pos] = w.x * sc;
                Bs[(kk + 1) * 192 + pos] = w.y * sc;
                Bs[(kk + 2) * 192 + pos] = w.z * sc;
                Bs[(kk + 3) * 192 + pos] = w.w * sc;
            }
        }
        __syncthreads();
        #pragma unroll 6
        for (int kk = 0; kk < KC; ++kk) {
            float4 a0 = *(const float4*)(&As[kk * ASP + rg * 8]);
            float4 a1 = *(const float4*)(&As[kk * ASP + rg * 8 + 4]);
            float4 v0 = *(const float4*)(&Bs[kk * 192 + cg * 12]);
            float4 v1 = *(const float4*)(&Bs[kk * 192 + cg * 12 + 4]);
            float2 v2 = *(const float2*)(&Bs[kk * 192 + cg * 12 + 8]);
            float av[8] = {a0.x, a0.y, a0.z, a0.w, a1.x, a1.y, a1.z, a1.w};
            float bv[10] = {v0.x, v0.y, v0.z, v0.w, v1.x, v1.y, v1.z, v1.w,
                            v2.x, v2.y};
            #pragma unroll
            for (int i = 0; i < 8; ++i)
                #pragma unroll
                for (int j = 0; j < 10; ++j) acc[i][j] += av[i] * bv[j];
        }
    }
    float* P = part + (size_t)(bt * NS + ks) * (128 * N_) + cg * 10;
    #pragma unroll
    for (int i = 0; i < 8; ++i) {
        float* Pr = P + (rg * 8 + i) * N_;
        #pragma unroll
        for (int j = 0; j < 5; ++j)
            *(float2*)(Pr + j * 2) = make_float2(acc[i][j * 2], acc[i][j * 2 + 1]);
    }
}

// ---------------------------------------------------------------------------
// one b-row per block (grid 256); 160 outputs; 128-way split-K sum + squash
__global__ void k_reduce(const float* __restrict__ part, float* __restrict__ out) {
    const int tid = threadIdx.x, b = blockIdx.x;
    if (tid < 160) {
        int bt = b >> 7, row = b & 127;
        const float* p = part + (size_t)bt * NS * (128 * N_) + row * N_ + tid;
        float s = 0.0f;
        #pragma unroll 8
        for (int ks = 0; ks < NS; ++ks) s += p[(size_t)ks * (128 * N_)];
        out[b * N_ + tid] = s * fabsf(s) / (1.0f + s * s);  // elementwise squash
    }
}

// ---------------------------------------------------------------------------
// per block (kt 0..127: 72 k-rows = 9 routes; bh 0..1: 128 b):
//   G_partial[72x160] = sum_{b-half} X^T V  (regs, 4 b-stages of 32)
//   -> LDS -> bij[r,c] += (1/B) sum_{o,i} W[r,c,o,i]*G[...]  (atomicAdd)
__global__ __launch_bounds__(256) void k_gtdot(const float* __restrict__ X,
                                               const float* __restrict__ W,
                                               const float* __restrict__ V,
                                               float* __restrict__ bij) {
    __shared__ float L[72 * 165];    // 47.5 KB; union: staging | G-tile
    float* Xs = L;                   // [32][96]  (8 groups x 12)
    float* Vs = L + 3072;            // [160][33] transposed
    float* LG = L;                   // [72][165]
    const int tid = threadIdx.x;
    const int kt = blockIdx.x >> 1, bh = blockIdx.x & 1;
    const int k0 = kt * 72, r0 = kt * 9, b0 = bh * 128;
    const int rg = tid >> 5;   // 8 groups x 9 k-rows
    const int cg = tid & 31;   // 32 groups x 5 n-cols
    float acc[9][5];
    #pragma unroll
    for (int i = 0; i < 9; ++i)
        #pragma unroll
        for (int j = 0; j < 5; ++j) acc[i][j] = 0.0f;

    for (int sb = 0; sb < 4; ++sb) {
        __syncthreads();
        const int bb0 = b0 + sb * 32;
        #pragma unroll
        for (int j = 0; j < 3; ++j) {           // X: 576 float4
            int q = j * 256 + tid;
            if (q < 576) {
                int bb = q / 18, kf = q - bb * 18;
                float4 a = *(const float4*)(X + (size_t)(bb0 + bb) * K_ + k0 + kf * 4);
                float c4[4] = {a.x, a.y, a.z, a.w};
                #pragma unroll
                for (int m = 0; m < 4; ++m) {
                    int kk = kf * 4 + m;
                    int gp = kk / 9;
                    Xs[bb * 96 + gp * 12 + (kk - gp * 9)] = c4[m];
                }
            }
        }
        #pragma unroll
        for (int j = 0; j < 5; ++j) {           // V: 1280 float4, transpose
            int q = j * 256 + tid;
            int bb = q / 40, nf = q - bb * 40;
            float4 v = *(const float4*)(V + (size_t)(bb0 + bb) * N_ + nf * 4);
            int n = nf * 4;
            Vs[(n + 0) * 33 + bb] = v.x;
            Vs[(n + 1) * 33 + bb] = v.y;
            Vs[(n + 2) * 33 + bb] = v.z;
            Vs[(n + 3) * 33 + bb] = v.w;
        }
        __syncthreads();
        #pragma unroll 4
        for (int b = 0; b < 32; ++b) {
            float4 x0 = *(const float4*)(&Xs[b * 96 + rg * 12]);
            float4 x1 = *(const float4*)(&Xs[b * 96 + rg * 12 + 4]);
            float x8 = Xs[b * 96 + rg * 12 + 8];
            float xr[9] = {x0.x, x0.y, x0.z, x0.w, x1.x, x1.y, x1.z, x1.w, x8};
            float bv[5];
            #pragma unroll
            for (int j = 0; j < 5; ++j) bv[j] = Vs[(cg * 5 + j) * 33 + b];
            #pragma unroll
            for (int i = 0; i < 9; ++i)
                #pragma unroll
                for (int j = 0; j < 5; ++j) acc[i][j] += xr[i] * bv[j];
        }
    }
    // G tile -> LDS (overwrites staging), stride 165 breaks pow2 banks
    __syncthreads();
    #pragma unroll
    for (int i = 0; i < 9; ++i)
        #pragma unroll
        for (int j = 0; j < 5; ++j)
            LG[(rg * 9 + i) * 165 + cg * 5 + j] = acc[i][j];
    __syncthreads();
    if (tid < 90) {
        int rl = tid / 10, c = tid - rl * 10;
        int r = r0 + rl;
        const float4* wp = (const float4*)(W + (size_t)r * 1280 + c * 128);
        float s = 0.0f;
        #pragma unroll
        for (int o = 0; o < 16; ++o) {
            float4 wa = wp[o * 2], wb = wp[o * 2 + 1];
            const float* g = &LG[(rl * 8) * 165 + c * 16 + o];
            s += wa.x * g[0]       + wa.y * g[165]     + wa.z * g[2 * 165] +
                 wa.w * g[3 * 165] + wb.x * g[4 * 165] + wb.y * g[5 * 165] +
                 wb.z * g[6 * 165] + wb.w * g[7 * 165];
        }
        atomicAdd(&bij[r * 10 + c], s * (1.0f / B_));
    }
}

// ---------------------------------------------------------------------------
extern "C" void kernel_launch(void* const* d_in, const int* in_sizes, int n_in,
                              void* d_out, int out_size, void* d_ws, size_t ws_size,
                              hipStream_t stream) {
    const float* x = (const float*)d_in[0];   // (256, 1152, 8)
    const float* W = (const float*)d_in[1];   // (1152, 10, 16, 8)
    float* ws   = (float*)d_ws;
    float* part = ws;
    float* bij  = ws + PART_SZ;
    float* vws  = bij + BIJ_SZ;
    float* outf = (float*)d_out;

    for (int it = 0; it < 3; ++it) {
        k_gemm<<<256, 256, 0, stream>>>(x, W, bij, part, it);
        k_reduce<<<256, 256, 0, stream>>>(part, (it == 2) ? outf : vws);
        if (it < 2) k_gtdot<<<256, 256, 0, stream>>>(x, W, vws, bij);
    }
}